// Round 7
// baseline (525.805 us; speedup 1.0000x reference)
//
#include <hip/hip_runtime.h>
#include <cstdint>

typedef unsigned short u16t;
typedef float v4f __attribute__((ext_vector_type(4)));
typedef short v8s __attribute__((ext_vector_type(8)));

#define HIDDEN 2048
#define NHEAD 16
#define HDIM 128
#define SEQ 2048
#define BATCH 2
#define MROWS (BATCH * SEQ) /* 4096 */

__device__ __forceinline__ float bf2f(u16t u) {
  return __builtin_bit_cast(float, (uint32_t)((uint32_t)u << 16));
}
__device__ __forceinline__ u16t f2bf(float f) {
  uint32_t u = __builtin_bit_cast(uint32_t, f);
  u += 0x7FFFu + ((u >> 16) & 1u);
  return (u16t)(u >> 16);
}
__device__ __forceinline__ ushort4 f2bf4(float4 v) {
  ushort4 r;
  r.x = f2bf(v.x); r.y = f2bf(v.y); r.z = f2bf(v.z); r.w = f2bf(v.w);
  return r;
}

// async global->LDS, 16B per lane. LDS dest must be wave-uniform base + lane*16.
__device__ __forceinline__ void gld_lds16(const u16t* g, u16t* l) {
  __builtin_amdgcn_global_load_lds(
      (const __attribute__((address_space(1))) uint32_t*)g,
      (__attribute__((address_space(3))) uint32_t*)l, 16, 0, 0);
}

// ---------------------------------------------------------------------------
// fp32 -> bf16 elementwise convert (8 elems/thread)
// ---------------------------------------------------------------------------
__global__ __launch_bounds__(256) void cvt_bf16(const float* __restrict__ src,
                                                u16t* __restrict__ dst, int n8) {
  int i = blockIdx.x * 256 + threadIdx.x;
  if (i < n8) {
    float4 a = ((const float4*)src)[2 * i];
    float4 b = ((const float4*)src)[2 * i + 1];
    union { ushort4 h[2]; uint4 u; } pk;
    pk.h[0] = f2bf4(a);
    pk.h[1] = f2bf4(b);
    ((uint4*)dst)[i] = pk.u;
  }
}

// ---------------------------------------------------------------------------
// GEMM (m97 structure): C[m,n] = sum_k A[m,k] * B[n,k]
// A, B bf16 staged via global_load_lds (16B); C fp32 or bf16.
// 128x128 tile, BK=32, 256 thr = 4 waves 2x2.
// ---------------------------------------------------------------------------
template <int B_BF16, int OUT_F32>
__global__ __launch_bounds__(256) void gemm_a16(const u16t* __restrict__ A,
                                                const void* __restrict__ Bp,
                                                void* __restrict__ Cp) {
  __shared__ u16t As[128 * 32];
  __shared__ u16t Bs[128 * 32];

  const int n0 = blockIdx.x * 128;
  const int m0 = blockIdx.y * 128;
  const int t = threadIdx.x;
  const int lane = t & 63;
  const int w = t >> 6;
  const int wm = w & 1;
  const int wn = w >> 1;
  const int l15 = lane & 15;
  const int quad = lane >> 4;

  v4f acc[4][4];
#pragma unroll
  for (int i = 0; i < 4; ++i)
#pragma unroll
    for (int j = 0; j < 4; ++j) acc[i][j] = (v4f){0.f, 0.f, 0.f, 0.f};

  for (int kb = 0; kb < HIDDEN; kb += 32) {
#pragma unroll
    for (int j = 0; j < 2; ++j) {
      int idx = t + j * 256;
      int row = idx >> 2;
      int ch = (idx & 3) * 8;
      gld_lds16(&A[(size_t)(m0 + row) * HIDDEN + kb + ch], &As[idx * 8]);
      if (B_BF16)
        gld_lds16(&((const u16t*)Bp)[(size_t)(n0 + row) * HIDDEN + kb + ch], &Bs[idx * 8]);
    }
    if (!B_BF16) {
      const float* B = (const float*)Bp;
#pragma unroll
      for (int j = 0; j < 4; ++j) {
        int idx = t + j * 256;
        int row = idx >> 3;
        int c4 = (idx & 7) * 4;
        float4 bv = *(const float4*)&B[(size_t)(n0 + row) * HIDDEN + kb + c4];
        *(ushort4*)&Bs[row * 32 + c4] = f2bf4(bv);
      }
    }
    __syncthreads();

    v8s af[4], bf[4];
#pragma unroll
    for (int mt = 0; mt < 4; ++mt)
      af[mt] = *(const v8s*)&As[(wm * 64 + mt * 16 + l15) * 32 + quad * 8];
#pragma unroll
    for (int nt = 0; nt < 4; ++nt)
      bf[nt] = *(const v8s*)&Bs[(wn * 64 + nt * 16 + l15) * 32 + quad * 8];

#pragma unroll
    for (int mt = 0; mt < 4; ++mt)
#pragma unroll
      for (int nt = 0; nt < 4; ++nt)
        acc[mt][nt] = __builtin_amdgcn_mfma_f32_16x16x32_bf16(af[mt], bf[nt], acc[mt][nt], 0, 0, 0);
    __syncthreads();
  }

#pragma unroll
  for (int mt = 0; mt < 4; ++mt) {
#pragma unroll
    for (int nt = 0; nt < 4; ++nt) {
      int col = n0 + wn * 64 + nt * 16 + l15;
#pragma unroll
      for (int r = 0; r < 4; ++r) {
        int row = m0 + wm * 64 + mt * 16 + quad * 4 + r;
        if (OUT_F32)
          ((float*)Cp)[(size_t)row * HIDDEN + col] = acc[mt][nt][r];
        else
          ((u16t*)Cp)[(size_t)row * HIDDEN + col] = f2bf(acc[mt][nt][r]);
      }
    }
  }
}

// ---------------------------------------------------------------------------
// V-projection GEMM with TRANSPOSED bf16 output vt[n][m].
// ---------------------------------------------------------------------------
template <int B_BF16>
__global__ __launch_bounds__(256) void gemm_vt(const u16t* __restrict__ A,
                                               const void* __restrict__ Bp,
                                               u16t* __restrict__ VtOut) {
  __shared__ u16t As[128 * 32];
  __shared__ u16t Bs[128 * 32];
  __shared__ u16t Ct[128 * 136];

  const int n0 = blockIdx.x * 128;
  const int m0 = blockIdx.y * 128;
  const int t = threadIdx.x;
  const int lane = t & 63;
  const int w = t >> 6;
  const int wm = w & 1;
  const int wn = w >> 1;
  const int l15 = lane & 15;
  const int quad = lane >> 4;

  v4f acc[4][4];
#pragma unroll
  for (int i = 0; i < 4; ++i)
#pragma unroll
    for (int j = 0; j < 4; ++j) acc[i][j] = (v4f){0.f, 0.f, 0.f, 0.f};

  for (int kb = 0; kb < HIDDEN; kb += 32) {
#pragma unroll
    for (int j = 0; j < 2; ++j) {
      int idx = t + j * 256;
      int row = idx >> 2;
      int ch = (idx & 3) * 8;
      gld_lds16(&A[(size_t)(m0 + row) * HIDDEN + kb + ch], &As[idx * 8]);
      if (B_BF16)
        gld_lds16(&((const u16t*)Bp)[(size_t)(n0 + row) * HIDDEN + kb + ch], &Bs[idx * 8]);
    }
    if (!B_BF16) {
      const float* B = (const float*)Bp;
#pragma unroll
      for (int j = 0; j < 4; ++j) {
        int idx = t + j * 256;
        int row = idx >> 3;
        int c4 = (idx & 7) * 4;
        float4 bv = *(const float4*)&B[(size_t)(n0 + row) * HIDDEN + kb + c4];
        *(ushort4*)&Bs[row * 32 + c4] = f2bf4(bv);
      }
    }
    __syncthreads();

    v8s af[4], bf[4];
#pragma unroll
    for (int mt = 0; mt < 4; ++mt)
      af[mt] = *(const v8s*)&As[(wm * 64 + mt * 16 + l15) * 32 + quad * 8];
#pragma unroll
    for (int nt = 0; nt < 4; ++nt)
      bf[nt] = *(const v8s*)&Bs[(wn * 64 + nt * 16 + l15) * 32 + quad * 8];

#pragma unroll
    for (int mt = 0; mt < 4; ++mt)
#pragma unroll
      for (int nt = 0; nt < 4; ++nt)
        acc[mt][nt] = __builtin_amdgcn_mfma_f32_16x16x32_bf16(af[mt], bf[nt], acc[mt][nt], 0, 0, 0);
    __syncthreads();
  }

#pragma unroll
  for (int mt = 0; mt < 4; ++mt)
#pragma unroll
    for (int nt = 0; nt < 4; ++nt)
#pragma unroll
      for (int r = 0; r < 4; ++r)
        Ct[(wn * 64 + nt * 16 + l15) * 136 + (wm * 64 + mt * 16 + quad * 4 + r)] =
            f2bf(acc[mt][nt][r]);
  __syncthreads();

#pragma unroll
  for (int j = 0; j < 8; ++j) {
    int idx = t + j * 256;
    int nl = idx >> 4;
    int mc = idx & 15;
    *(uint4*)&VtOut[(size_t)(n0 + nl) * MROWS + m0 + mc * 8] =
        *(const uint4*)&Ct[nl * 136 + mc * 8];
  }
}

// ---------------------------------------------------------------------------
// RoPE in-place on q and k (bf16, [m][h*128+d])
// ---------------------------------------------------------------------------
__global__ __launch_bounds__(256) void rope_k(u16t* __restrict__ q, u16t* __restrict__ k) {
  int idx = blockIdx.x * 256 + threadIdx.x;
  int i = idx & 63;
  int h = (idx >> 6) & (NHEAD - 1);
  int m = idx >> 10;
  int s = m & (SEQ - 1);
  float inv = __expf(-(float)i * 0.14391156831212787f);
  float th = (float)s * inv;
  float sn, cs;
  __sincosf(th, &sn, &cs);
  size_t base = (size_t)m * HIDDEN + h * HDIM + i;
  {
    float a = bf2f(q[base]), b = bf2f(q[base + 64]);
    q[base] = f2bf(a * cs - b * sn);
    q[base + 64] = f2bf(b * cs + a * sn);
  }
  {
    float a = bf2f(k[base]), b = bf2f(k[base + 64]);
    k[base] = f2bf(a * cs - b * sn);
    k[base + 64] = f2bf(b * cs + a * sn);
  }
}

// ---------------------------------------------------------------------------
// Flash attention v3.
//  - grid (32 bh, 8 a): linear id = bh + 32*a -> XCD = bh%8, so all 8 blocks
//    sharing one (b,h) co-locate on one XCD; K/V (1 MB/head) become
//    L2-resident (4 heads x 1 MB = 4 MB = one XCD L2).
//  - register prefetch: next K/V tile loaded into VGPRs during current step's
//    compute, ds_written at top of next step (classic 2-stage pipeline).
// Block: 512 thr = 8 waves x 16 q-rows, Q tile 128, KV step 64.
// ---------------------------------------------------------------------------
__global__ __launch_bounds__(512) void flash3(const u16t* __restrict__ Q,
                                              const u16t* __restrict__ K,
                                              const u16t* __restrict__ Vt,
                                              u16t* __restrict__ O) {
  __shared__ u16t smem[27136];
  u16t* Ks = smem;              // [64][136]
  u16t* Vs = smem + 8704;       // [128][72]
  u16t* Ps = smem + 17920;      // [128][72]

  const int bh = blockIdx.x;    // fastest dim -> same-bh blocks on same XCD
  const int a = blockIdx.y;
  const int b = bh >> 4;
  const int h = bh & 15;
  const size_t rowb = (size_t)b * SEQ;
  const u16t* vtg = Vt + (size_t)h * HDIM * MROWS + (size_t)b * SEQ;

  const int t = threadIdx.x;
  const int lane = t & 63;
  const int w = t >> 6;
  const int l15 = lane & 15;
  const int quad = lane >> 4;
  const float C2 = 0.12751743f;  // log2(e)/sqrt(128)
  const float NEG = -3.0e38f;

  // per-thread staging slots (fixed)
  const int kr0 = t >> 4;        // K row 0..31 (+32)
  const int kch = (t & 15) * 8;  // K col chunk
  const int vd0 = t >> 3;        // V d-row 0..63 (+64)
  const int vkc = (t & 7) * 8;   // V kv chunk

  for (int half = 0; half < 2; ++half) {
    const int qt = half ? (15 - a) : a;
    const int q0 = qt * 128;

    // ---- stage Q [128][136], pull fragments ----
#pragma unroll
    for (int j = 0; j < 4; ++j) {
      int idx = t + j * 512;
      int row = idx >> 4;
      int ch = (idx & 15) * 8;
      *(uint4*)&smem[row * 136 + ch] =
          *(const uint4*)&Q[(rowb + q0 + row) * HIDDEN + h * HDIM + ch];
    }
    __syncthreads();
    v8s qf[4];
#pragma unroll
    for (int ks = 0; ks < 4; ++ks)
      qf[ks] = *(const v8s*)&smem[(w * 16 + l15) * 136 + ks * 32 + quad * 8];
    __syncthreads();

    float mi[4], li[4];
    v4f o[8];
#pragma unroll
    for (int r = 0; r < 4; ++r) { mi[r] = NEG; li[r] = 0.f; }
#pragma unroll
    for (int nt = 0; nt < 8; ++nt) o[nt] = (v4f){0.f, 0.f, 0.f, 0.f};

    const int nsteps = 2 * (qt + 1);

    // ---- preload step 0 into registers ----
    uint4 kpre[2], vpre[2];
#pragma unroll
    for (int j = 0; j < 2; ++j) {
      kpre[j] = *(const uint4*)&K[(rowb + kr0 + j * 32) * HIDDEN + h * HDIM + kch];
      vpre[j] = *(const uint4*)&vtg[(size_t)(vd0 + j * 64) * MROWS + vkc];
    }

    for (int kt = 0; kt < nsteps; ++kt) {
      const int kv0 = kt * 64;
      // ---- commit prefetched tile to LDS ----
#pragma unroll
      for (int j = 0; j < 2; ++j) {
        *(uint4*)&Ks[(kr0 + j * 32) * 136 + kch] = kpre[j];
        *(uint4*)&Vs[(vd0 + j * 64) * 72 + vkc] = vpre[j];
      }
      // ---- issue next step's loads (in flight during compute) ----
      if (kt + 1 < nsteps) {
        const int kvn = kv0 + 64;
#pragma unroll
        for (int j = 0; j < 2; ++j) {
          kpre[j] = *(const uint4*)&K[(rowb + kvn + kr0 + j * 32) * HIDDEN + h * HDIM + kch];
          vpre[j] = *(const uint4*)&vtg[(size_t)(vd0 + j * 64) * MROWS + kvn + vkc];
        }
      }
      __syncthreads();

      // ---- S = Q K^T ----
      v4f sc[4];
#pragma unroll
      for (int nt = 0; nt < 4; ++nt) {
        sc[nt] = (v4f){0.f, 0.f, 0.f, 0.f};
#pragma unroll
        for (int ks = 0; ks < 4; ++ks) {
          v8s kf = *(const v8s*)&Ks[(nt * 16 + l15) * 136 + ks * 32 + quad * 8];
          sc[nt] = __builtin_amdgcn_mfma_f32_16x16x32_bf16(qf[ks], kf, sc[nt], 0, 0, 0);
        }
      }

      // ---- online softmax ----
      const bool mm = (kv0 + 64 > q0);
#pragma unroll
      for (int r = 0; r < 4; ++r) {
        int row_g = q0 + w * 16 + quad * 4 + r;
        float sv[4];
#pragma unroll
        for (int nt = 0; nt < 4; ++nt) {
          sv[nt] = sc[nt][r];
          if (mm && (kv0 + nt * 16 + l15 > row_g)) sv[nt] = NEG;
        }
        float rm = fmaxf(fmaxf(sv[0], sv[1]), fmaxf(sv[2], sv[3]));
#pragma unroll
        for (int off = 1; off < 16; off <<= 1) rm = fmaxf(rm, __shfl_xor(rm, off));
        float mn = fmaxf(mi[r], rm);
        float alpha = exp2f((mi[r] - mn) * C2);
        float ps = 0.f;
        u16t pb[4];
#pragma unroll
        for (int nt = 0; nt < 4; ++nt) {
          float p = exp2f((sv[nt] - mn) * C2);
          ps += p;
          pb[nt] = f2bf(p);
        }
#pragma unroll
        for (int off = 1; off < 16; off <<= 1) ps += __shfl_xor(ps, off);
        li[r] = li[r] * alpha + ps;
        mi[r] = mn;
#pragma unroll
        for (int nt = 0; nt < 8; ++nt) o[nt][r] *= alpha;
        int pr = (w * 16 + quad * 4 + r) * 72;
#pragma unroll
        for (int nt = 0; nt < 4; ++nt) Ps[pr + nt * 16 + l15] = pb[nt];
      }

      // ---- O += P V (P rows are wave-private: no barrier needed) ----
#pragma unroll
      for (int ks = 0; ks < 2; ++ks) {
        v8s pf = *(const v8s*)&Ps[(w * 16 + l15) * 72 + ks * 32 + quad * 8];
#pragma unroll
        for (int nt = 0; nt < 8; ++nt) {
          v8s vf = *(const v8s*)&Vs[(nt * 16 + l15) * 72 + ks * 32 + quad * 8];
          o[nt] = __builtin_amdgcn_mfma_f32_16x16x32_bf16(pf, vf, o[nt], 0, 0, 0);
        }
      }
      __syncthreads();  // LDS free for next step's commit
    }

    // ---- epilogue ----
#pragma unroll
    for (int r = 0; r < 4; ++r) {
      float inv = 1.0f / li[r];
      size_t row = rowb + q0 + w * 16 + quad * 4 + r;
#pragma unroll
      for (int nt = 0; nt < 8; ++nt)
        O[row * HIDDEN + h * HDIM + nt * 16 + l15] = f2bf(o[nt][r] * inv);
    }
    __syncthreads();
  }
}

// ---------------------------------------------------------------------------
extern "C" void kernel_launch(void* const* d_in, const int* in_sizes, int n_in,
                              void* d_out, int out_size, void* d_ws, size_t ws_size,
                              hipStream_t stream) {
  const float* X = (const float*)d_in[0];
  const float* Wq = (const float*)d_in[3];
  const float* Wk = (const float*)d_in[4];
  const float* Wv = (const float*)d_in[5];
  const float* Wo = (const float*)d_in[6];
  float* out = (float*)d_out;

  char* wsb = (char*)d_ws;
  const size_t MB = 1024 * 1024;
  u16t* xb = (u16t*)(wsb + 0 * MB);
  u16t* q = (u16t*)(wsb + 16 * MB);
  u16t* k = (u16t*)(wsb + 32 * MB);
  u16t* vt = (u16t*)(wsb + 48 * MB);
  u16t* a = xb;  // flash out aliases xb (xb dead by then)

  dim3 blk(256);
  dim3 gg(HIDDEN / 128, MROWS / 128);  // (16, 32)
  dim3 fg(BATCH * NHEAD, 8);           // bh fastest -> XCD locality
  const int XN8 = MROWS * HIDDEN / 8;
  const int WN8 = HIDDEN * HIDDEN / 8;

  cvt_bf16<<<(XN8 + 255) / 256, blk, 0, stream>>>(X, xb, XN8);

  if (ws_size >= 96 * MB) {
    u16t* wqb = (u16t*)(wsb + 64 * MB);
    u16t* wkb = (u16t*)(wsb + 72 * MB);
    u16t* wvb = (u16t*)(wsb + 80 * MB);
    u16t* wob = (u16t*)(wsb + 88 * MB);
    cvt_bf16<<<(WN8 + 255) / 256, blk, 0, stream>>>(Wq, wqb, WN8);
    cvt_bf16<<<(WN8 + 255) / 256, blk, 0, stream>>>(Wk, wkb, WN8);
    cvt_bf16<<<(WN8 + 255) / 256, blk, 0, stream>>>(Wv, wvb, WN8);
    cvt_bf16<<<(WN8 + 255) / 256, blk, 0, stream>>>(Wo, wob, WN8);

    gemm_a16<1, 0><<<gg, blk, 0, stream>>>(xb, wqb, q);
    gemm_a16<1, 0><<<gg, blk, 0, stream>>>(xb, wkb, k);
    gemm_vt<1><<<gg, blk, 0, stream>>>(xb, wvb, vt);
    rope_k<<<(MROWS * NHEAD * 64) / 256, blk, 0, stream>>>(q, k);
    flash3<<<fg, dim3(512), 0, stream>>>(q, k, vt, a);
    gemm_a16<1, 1><<<gg, blk, 0, stream>>>(a, wob, out);
  } else {
    gemm_a16<0, 0><<<gg, blk, 0, stream>>>(xb, Wq, q);
    gemm_a16<0, 0><<<gg, blk, 0, stream>>>(xb, Wk, k);
    gemm_vt<0><<<gg, blk, 0, stream>>>(xb, Wv, vt);
    rope_k<<<(MROWS * NHEAD * 64) / 256, blk, 0, stream>>>(q, k);
    flash3<<<fg, dim3(512), 0, stream>>>(q, k, vt, a);
    gemm_a16<0, 1><<<gg, blk, 0, stream>>>(a, Wo, out);
  }
}